// Round 2
// baseline (1719.943 us; speedup 1.0000x reference)
//
#include <hip/hip_runtime.h>
#include <stdint.h>

#define NPIX   131072      // 32*64*64 per batch
#define HALFN  65536
#define KSEL   50
#define CAP_E  1024        // easy candidate cap (u >= THR)
#define CAP_H  2048        // hard prefix length / cap
#define THR    0.99f
#define SENT_HARD 0xFFFFFFFFu
#define SENT_NONE 0xFFFFFFFEu

__host__ __device__ __forceinline__ uint32_t rotl32(uint32_t v, int d) {
  return (v << d) | (v >> (32 - d));
}

// JAX Threefry-2x32 block (20 rounds), matches jax/_src/prng.py exactly.
__host__ __device__ __forceinline__ void tf_block(uint32_t k0, uint32_t k1,
                                                  uint32_t c0, uint32_t c1,
                                                  uint32_t& o0, uint32_t& o1) {
  uint32_t ks2 = k0 ^ k1 ^ 0x1BD11BDAu;
  uint32_t x0 = c0 + k0, x1 = c1 + k1;
#define TF_R(r) { x0 += x1; x1 = rotl32(x1, (r)); x1 ^= x0; }
  TF_R(13) TF_R(15) TF_R(26) TF_R(6)   x0 += k1;  x1 += ks2 + 1u;
  TF_R(17) TF_R(29) TF_R(16) TF_R(24)  x0 += ks2; x1 += k0  + 2u;
  TF_R(13) TF_R(15) TF_R(26) TF_R(6)   x0 += k0;  x1 += k1  + 3u;
  TF_R(17) TF_R(29) TF_R(16) TF_R(24)  x0 += k1;  x1 += ks2 + 4u;
  TF_R(13) TF_R(15) TF_R(26) TF_R(6)   x0 += ks2; x1 += k0  + 5u;
#undef TF_R
  o0 = x0; o1 = x1;
}

__global__ void k_zero(int* cnts, float* out) {
  int i = threadIdx.x;
  if (i < 8) cnts[i] = 0;
  if (i == 0) out[0] = 0.f;
}

// Pass 1: classify, Threefry uniform, compact candidates via global atomics.
// cnts[b*4 + {0:easy_total, 1:easy_cand, 2:hard_total, 3:hard_cand}]
__global__ void k_scores(const int* __restrict__ labels, const int* __restrict__ predict,
                         uint32_t* __restrict__ scores, uint64_t* __restrict__ ecand,
                         uint32_t* __restrict__ hcand, int* __restrict__ cnts,
                         uint32_t k00, uint32_t k01, uint32_t k10, uint32_t k11) {
  int gid = blockIdx.x * blockDim.x + threadIdx.x;
  if (gid >= 2 * NPIX) return;
  int b = gid >> 17;
  int n = gid & (NPIX - 1);
  int yh = labels[gid], yp = predict[gid];
  uint32_t sval;
  if (yh == 1 && yp == 1) {                 // easy positive
    uint32_t ka = b ? k10 : k00, kb = b ? k11 : k01;
    uint32_t o0, o1, bits;
    if (n < HALFN) { tf_block(ka, kb, (uint32_t)n, (uint32_t)(n + HALFN), o0, o1); bits = o0; }
    else           { tf_block(ka, kb, (uint32_t)(n - HALFN), (uint32_t)n, o0, o1); bits = o1; }
    float u = __uint_as_float((bits >> 9) | 0x3F800000u) - 1.0f;   // jax uniform [0,1)
    sval = __float_as_uint(u);
    atomicAdd(&cnts[b * 4 + 0], 1);
    if (u >= THR) {
      int p = atomicAdd(&cnts[b * 4 + 1], 1);
      if (p < CAP_E)
        ecand[b * CAP_E + p] = ((uint64_t)sval << 32) | (uint32_t)(~(uint32_t)n);
    }
  } else if (yh == 0 && yp == 0) {          // hard
    sval = SENT_HARD;
    atomicAdd(&cnts[b * 4 + 2], 1);
    if (n < CAP_H) {
      int p = atomicAdd(&cnts[b * 4 + 3], 1);
      hcand[b * CAP_H + p] = (uint32_t)n;   // p < CAP_H guaranteed (cands subset of prefix)
    }
  } else {
    sval = SENT_NONE;
  }
  scores[gid] = sval;
}

// Pass 2: one block per batch — LDS bitonic sorts over the candidate sets.
__global__ __launch_bounds__(1024) void k_select(const uint32_t* __restrict__ scores,
                                                 const uint64_t* __restrict__ ecand,
                                                 const uint32_t* __restrict__ hcand,
                                                 const int* __restrict__ cnts,
                                                 int* __restrict__ easy_out,
                                                 int* __restrict__ hard_out) {
  int b = blockIdx.x;
  int tid = threadIdx.x;
  int wv = tid >> 6, lane = tid & 63;
  __shared__ uint64_t se[CAP_E];     // 8 KB
  __shared__ uint32_t shd[CAP_H];    // 8 KB
  __shared__ uint64_t wred[16];
  __shared__ uint64_t s_win;

  int et = cnts[b * 4 + 0], ec = cnts[b * 4 + 1];
  int ht = cnts[b * 4 + 2], hc = cnts[b * 4 + 3];
  int eneed = et < KSEL ? et : KSEL;
  int hneed = ht < KSEL ? ht : KSEL;
  bool fast_easy = (ec <= CAP_E) && (ec >= eneed);
  bool fast_hard = (hc >= hneed);   // hc <= CAP_H always

  // ---------------- EASY ----------------
  if (fast_easy) {
    se[tid] = (tid < ec) ? ecand[b * CAP_E + tid] : 0ull;
    __syncthreads();
    for (int k2 = 2; k2 <= CAP_E; k2 <<= 1) {
      for (int j = k2 >> 1; j > 0; j >>= 1) {
        int ixj = tid ^ j;
        if (ixj > tid) {
          uint64_t a = se[tid], c = se[ixj];
          bool asc = ((tid & k2) == 0);
          if (asc ? (a > c) : (a < c)) { se[tid] = c; se[ixj] = a; }
        }
        __syncthreads();
      }
    }
    int take = ec < KSEL ? ec : KSEL;
    if (tid < take) easy_out[b * 64 + tid] = (int)(~(uint32_t)se[CAP_E - 1 - tid]);
    __syncthreads();
    if (tid == 0 && take < KSEL) {   // fewer than 50 easy: ascending non-easy tail
      int slot = take;
      for (int n = 0; n < NPIX && slot < KSEL; ++n)
        if (scores[b * NPIX + n] >= SENT_NONE) easy_out[b * 64 + slot++] = n;
    }
    __syncthreads();
  } else {
    // slow exact path (never taken on bench data): iterative global max-selection
    uint64_t prev = 0xFFFFFFFFFFFFFFFFull;
    int k = 0;
    for (; k < KSEL; ++k) {
      uint64_t lmax = 0;
      for (int i = tid; i < NPIX; i += 1024) {
        uint32_t v = scores[b * NPIX + i];
        if (v < SENT_NONE) {
          uint64_t key = ((uint64_t)v << 32) | (uint32_t)(~(uint32_t)i);
          if (key < prev && key > lmax) lmax = key;
        }
      }
      for (int off = 32; off; off >>= 1) {
        uint64_t o = __shfl_down(lmax, off);
        if (o > lmax) lmax = o;
      }
      if (lane == 0) wred[wv] = lmax;
      __syncthreads();
      if (tid == 0) {
        uint64_t m = 0;
        for (int w = 0; w < 16; ++w) if (wred[w] > m) m = wred[w];
        s_win = m;
      }
      __syncthreads();
      uint64_t win = s_win;
      __syncthreads();
      if (win == 0) break;
      if (tid == 0) easy_out[b * 64 + k] = (int)(~(uint32_t)win);
      prev = win;
    }
    if (tid == 0 && k < KSEL) {
      int slot = k;
      for (int n = 0; n < NPIX && slot < KSEL; ++n)
        if (scores[b * NPIX + n] >= SENT_NONE) easy_out[b * 64 + slot++] = n;
    }
    __syncthreads();
  }

  // ---------------- HARD ----------------
  if (fast_hard) {
    for (int m = tid; m < CAP_H; m += 1024)
      shd[m] = (m < hc) ? hcand[b * CAP_H + m] : 0xFFFFFFFFu;
    __syncthreads();
    for (int k2 = 2; k2 <= CAP_H; k2 <<= 1) {
      for (int j = k2 >> 1; j > 0; j >>= 1) {
        for (int m = tid; m < CAP_H; m += 1024) {
          int ixj = m ^ j;
          if (ixj > m) {
            uint32_t a = shd[m], c = shd[ixj];
            bool asc = ((m & k2) == 0);
            if (asc ? (a > c) : (a < c)) { shd[m] = c; shd[ixj] = a; }
          }
        }
        __syncthreads();
      }
    }
    int take = hc < KSEL ? hc : KSEL;
    if (tid < take) hard_out[b * 64 + tid] = (int)shd[tid];
    __syncthreads();
    if (tid == 0 && take < KSEL) {   // fewer than 50 hard: ascending non-hard tail
      int slot = take;
      for (int n = 0; n < NPIX && slot < KSEL; ++n)
        if (scores[b * NPIX + n] != SENT_HARD) hard_out[b * 64 + slot++] = n;
    }
    __syncthreads();
  } else {
    // slow exact path: iterative global min-selection over hard indices
    int prev = -1;
    int k = 0;
    for (; k < KSEL; ++k) {
      uint32_t lmin = 0xFFFFFFFFu;
      for (int i = tid; i < NPIX; i += 1024) {
        uint32_t v = scores[b * NPIX + i];
        if (v == SENT_HARD && i > prev && (uint32_t)i < lmin) lmin = (uint32_t)i;
      }
      for (int off = 32; off; off >>= 1) {
        uint32_t o = (uint32_t)__shfl_down(lmin, off);
        if (o < lmin) lmin = o;
      }
      if (lane == 0) wred[wv] = lmin;
      __syncthreads();
      if (tid == 0) {
        uint32_t m = 0xFFFFFFFFu;
        for (int w = 0; w < 16; ++w) if ((uint32_t)wred[w] < m) m = (uint32_t)wred[w];
        s_win = m;
      }
      __syncthreads();
      uint32_t win = (uint32_t)s_win;
      __syncthreads();
      if (win == 0xFFFFFFFFu) break;
      if (tid == 0) hard_out[b * 64 + k] = (int)win;
      prev = (int)win;
    }
    if (tid == 0 && k < KSEL) {
      int slot = k;
      for (int n = 0; n < NPIX && slot < KSEL; ++n)
        if (scores[b * NPIX + n] != SENT_HARD) hard_out[b * 64 + slot++] = n;
    }
    __syncthreads();
  }
}

// Pass 3: gather 200 rows of D=128 from feats (layout [B,D,N]) and L2-normalize.
__global__ void k_gather(const float* __restrict__ feats, const int* __restrict__ easy_out,
                         const int* __restrict__ hard_out, float* __restrict__ A) {
  int r = blockIdx.x;          // A[2i+v] = X_[v][i]
  int d = threadIdx.x;         // 0..127
  int v = r & 1, i = r >> 1;
  int n = (i < KSEL) ? easy_out[v * 64 + i] : hard_out[v * 64 + (i - KSEL)];
  float val = feats[((size_t)(v * 128 + d)) * NPIX + (size_t)n];
  float sq = val * val;
  for (int off = 32; off; off >>= 1) sq += __shfl_down(sq, off);
  __shared__ float wsum[2];
  __shared__ float s_inv;
  if ((d & 63) == 0) wsum[d >> 6] = sq;
  __syncthreads();
  if (d == 0) s_inv = 1.0f / fmaxf(sqrtf(wsum[0] + wsum[1]), 1e-12f);
  __syncthreads();
  A[r * 128 + d] = val * s_inv;
}

// Pass 4: per-row contrastive terms, atomically accumulated into the scalar out.
__global__ __launch_bounds__(256) void k_loss(const float* __restrict__ A,
                                              float* __restrict__ out) {
  int r = blockIdx.x;   // 0..199
  int c = threadIdx.x;  // 0..255
  __shared__ float arow[128];
  __shared__ float red[256];
  if (c < 128) arow[c] = A[r * 128 + c];
  __syncthreads();
  bool valid = c < 200;
  float logit = -1e30f;
  if (valid) {
    const float* Ac = A + c * 128;
    float dot = 0.f;
#pragma unroll 8
    for (int d = 0; d < 128; ++d) dot += arow[d] * Ac[d];
    logit = dot * 10.0f;      // / BASE_TEMP (0.1)
  }
  red[c] = logit;
  __syncthreads();
  for (int s = 128; s; s >>= 1) { if (c < s) { float o = red[c + s]; if (o > red[c]) red[c] = o; } __syncthreads(); }
  float M = red[0];
  __syncthreads();
  float e = valid ? expf(logit - M) : 0.f;
  bool sameblk = valid && ((r / 100) == (c / 100));
  red[c] = (valid && !sameblk) ? e : 0.f;   // neg_mask = 1 - mask0
  __syncthreads();
  for (int s = 128; s; s >>= 1) { if (c < s) red[c] += red[c + s]; __syncthreads(); }
  float neg = red[0];
  __syncthreads();
  bool msk = sameblk && !(r < 100 && c == r);   // mask0 * logits_mask
  red[c] = msk ? ((logit - M) - logf(e + neg)) : 0.f;
  __syncthreads();
  for (int s = 128; s; s >>= 1) { if (c < s) red[c] += red[c + s]; __syncthreads(); }
  if (c == 0) {
    float denom = (r < 100) ? 99.f : 100.f;
    // -(mean_lpp / TEMP).mean() accumulated across 200 rows
    atomicAdd(out, -(red[0] / denom) / (20.0f * 200.0f));
  }
}

extern "C" void kernel_launch(void* const* d_in, const int* in_sizes, int n_in,
                              void* d_out, int out_size, void* d_ws, size_t ws_size,
                              hipStream_t stream) {
  const float* feats  = (const float*)d_in[0];
  const int* labels   = (const int*)d_in[1];
  const int* predict  = (const int*)d_in[2];
  float* out = (float*)d_out;

  char* ws = (char*)d_ws;
  uint32_t* scores = (uint32_t*)ws;                            // 1 MiB
  uint64_t* ecand  = (uint64_t*)(ws + (size_t)2 * NPIX * 4);   // 2*1024 u64 = 16 KB
  uint32_t* hcand  = (uint32_t*)((char*)ecand + 2 * CAP_E * 8);// 2*2048 u32 = 16 KB
  int* cnts  = (int*)((char*)hcand + 2 * CAP_H * 4);           // 8 int
  int* easy  = cnts + 8;                                       // 2*64 int
  int* hard  = easy + 2 * 64;                                  // 2*64 int
  float* A   = (float*)(hard + 2 * 64);                        // 200*128 f32

  // Batch keys: key(42) = (0,42); split -> blocks (0,2) and (1,3) (host-side, deterministic).
  uint32_t a0, a1, b0, b1;
  tf_block(0u, 42u, 0u, 2u, a0, a1);
  tf_block(0u, 42u, 1u, 3u, b0, b1);
  // keys[0] = (a0, b0), keys[1] = (a1, b1)

  k_zero<<<1, 64, 0, stream>>>(cnts, out);
  k_scores<<<(2 * NPIX) / 512, 512, 0, stream>>>(labels, predict, scores, ecand, hcand, cnts, a0, b0, a1, b1);
  k_select<<<2, 1024, 0, stream>>>(scores, ecand, hcand, cnts, easy, hard);
  k_gather<<<200, 128, 0, stream>>>(feats, easy, hard, A);
  k_loss<<<200, 256, 0, stream>>>(A, out);
}

// Round 3
// 216.036 us; speedup vs baseline: 7.9614x; 7.9614x over previous
//
#include <hip/hip_runtime.h>
#include <stdint.h>

#define NPIX   131072      // 32*64*64 per batch
#define HALFN  65536
#define KSEL   50
#define CAP_E  1024        // easy candidate cap (u >= THR)
#define CAP_H  2048        // hard prefix length / cap
#define THR    0.99f
#define CSTR   32          // counter stride in ints (128 B: one cacheline per counter)
#define SENT_HARD 0xFFFFFFFFu
#define SENT_NONE 0xFFFFFFFEu

__host__ __device__ __forceinline__ uint32_t rotl32(uint32_t v, int d) {
  return (v << d) | (v >> (32 - d));
}

// JAX Threefry-2x32 block (20 rounds), matches jax/_src/prng.py exactly.
__host__ __device__ __forceinline__ void tf_block(uint32_t k0, uint32_t k1,
                                                  uint32_t c0, uint32_t c1,
                                                  uint32_t& o0, uint32_t& o1) {
  uint32_t ks2 = k0 ^ k1 ^ 0x1BD11BDAu;
  uint32_t x0 = c0 + k0, x1 = c1 + k1;
#define TF_R(r) { x0 += x1; x1 = rotl32(x1, (r)); x1 ^= x0; }
  TF_R(13) TF_R(15) TF_R(26) TF_R(6)   x0 += k1;  x1 += ks2 + 1u;
  TF_R(17) TF_R(29) TF_R(16) TF_R(24)  x0 += ks2; x1 += k0  + 2u;
  TF_R(13) TF_R(15) TF_R(26) TF_R(6)   x0 += k0;  x1 += k1  + 3u;
  TF_R(17) TF_R(29) TF_R(16) TF_R(24)  x0 += k1;  x1 += ks2 + 4u;
  TF_R(13) TF_R(15) TF_R(26) TF_R(6)   x0 += ks2; x1 += k0  + 5u;
#undef TF_R
  o0 = x0; o1 = x1;
}

__global__ void k_zero(int* cnts, float* out) {
  int i = threadIdx.x;
  if (i < 8 * CSTR) cnts[i] = 0;
  if (i == 0) out[0] = 0.f;
}

// Pass 1: classify, Threefry uniform, block-aggregated compaction.
// cnts[(b*4 + {0:easy_total,1:easy_cand,2:hard_total,3:hard_cand}) * CSTR]
__global__ __launch_bounds__(512) void k_scores(
    const int* __restrict__ labels, const int* __restrict__ predict,
    uint32_t* __restrict__ scores, uint64_t* __restrict__ ecand,
    uint32_t* __restrict__ hcand, int* __restrict__ cnts,
    uint32_t k00, uint32_t k01, uint32_t k10, uint32_t k11) {
  int gid = blockIdx.x * blockDim.x + threadIdx.x;   // grid exact
  int b = gid >> 17;
  int n = gid & (NPIX - 1);
  int tid = threadIdx.x, wv = tid >> 6, lane = tid & 63;
  int yh = labels[gid], yp = predict[gid];
  bool is_easy = (yh == 1 && yp == 1);
  bool is_hard = (yh == 0 && yp == 0);
  uint32_t sval = SENT_NONE;
  float u = -1.f;
  if (is_easy) {
    uint32_t ka = b ? k10 : k00, kb = b ? k11 : k01;
    uint32_t o0, o1, bits;
    if (n < HALFN) { tf_block(ka, kb, (uint32_t)n, (uint32_t)(n + HALFN), o0, o1); bits = o0; }
    else           { tf_block(ka, kb, (uint32_t)(n - HALFN), (uint32_t)n, o0, o1); bits = o1; }
    u = __uint_as_float((bits >> 9) | 0x3F800000u) - 1.0f;   // jax uniform [0,1)
    sval = __float_as_uint(u);
  } else if (is_hard) {
    sval = SENT_HARD;
  }
  scores[gid] = sval;

  bool cand_e = is_easy && (u >= THR);
  bool cand_h = is_hard && (n < CAP_H);
  uint64_t bal_e  = __ballot(is_easy), bal_h  = __ballot(is_hard);
  uint64_t bal_ec = __ballot(cand_e),  bal_hc = __ballot(cand_h);

  __shared__ int we[8], wh[8], wec[8], whc[8];
  __shared__ int base_ec, base_hc;
  if (lane == 0) {
    we[wv]  = __popcll(bal_e);  wh[wv]  = __popcll(bal_h);
    wec[wv] = __popcll(bal_ec); whc[wv] = __popcll(bal_hc);
  }
  __syncthreads();
  if (tid == 0) {
    int te = 0, th = 0, tec = 0, thc = 0;
    for (int w = 0; w < 8; ++w) { te += we[w]; th += wh[w]; tec += wec[w]; thc += whc[w]; }
    if (te) atomicAdd(&cnts[(b * 4 + 0) * CSTR], te);
    if (th) atomicAdd(&cnts[(b * 4 + 2) * CSTR], th);
    base_ec = tec ? atomicAdd(&cnts[(b * 4 + 1) * CSTR], tec) : 0;
    base_hc = thc ? atomicAdd(&cnts[(b * 4 + 3) * CSTR], thc) : 0;
  }
  __syncthreads();
  if (cand_e) {
    int pre = 0;
    for (int w = 0; w < wv; ++w) pre += wec[w];
    int p = base_ec + pre + __popcll(bal_ec & ((1ull << lane) - 1));
    if (p < CAP_E)
      ecand[b * CAP_E + p] = ((uint64_t)sval << 32) | (uint32_t)(~(uint32_t)n);
  }
  if (cand_h) {
    int pre = 0;
    for (int w = 0; w < wv; ++w) pre += whc[w];
    int p = base_hc + pre + __popcll(bal_hc & ((1ull << lane) - 1));
    hcand[b * CAP_H + p] = (uint32_t)n;   // <= CAP_H guaranteed (subset of n<CAP_H)
  }
}

// Pass 2: one block per batch — LDS bitonic sorts over the candidate sets.
__global__ __launch_bounds__(1024) void k_select(const uint32_t* __restrict__ scores,
                                                 const uint64_t* __restrict__ ecand,
                                                 const uint32_t* __restrict__ hcand,
                                                 const int* __restrict__ cnts,
                                                 int* __restrict__ easy_out,
                                                 int* __restrict__ hard_out) {
  int b = blockIdx.x;
  int tid = threadIdx.x;
  int wv = tid >> 6, lane = tid & 63;
  __shared__ uint64_t se[CAP_E];     // 8 KB
  __shared__ uint32_t shd[CAP_H];    // 8 KB
  __shared__ uint64_t wred[16];
  __shared__ uint64_t s_win;

  int et = cnts[(b * 4 + 0) * CSTR], ec = cnts[(b * 4 + 1) * CSTR];
  int ht = cnts[(b * 4 + 2) * CSTR], hc = cnts[(b * 4 + 3) * CSTR];
  int eneed = et < KSEL ? et : KSEL;
  int hneed = ht < KSEL ? ht : KSEL;
  bool fast_easy = (ec <= CAP_E) && (ec >= eneed);
  bool fast_hard = (hc >= hneed);   // hc <= CAP_H always

  // ---------------- EASY ----------------
  if (fast_easy) {
    se[tid] = (tid < ec) ? ecand[b * CAP_E + tid] : 0ull;
    __syncthreads();
    for (int k2 = 2; k2 <= CAP_E; k2 <<= 1) {
      for (int j = k2 >> 1; j > 0; j >>= 1) {
        int ixj = tid ^ j;
        if (ixj > tid) {
          uint64_t a = se[tid], c = se[ixj];
          bool asc = ((tid & k2) == 0);
          if (asc ? (a > c) : (a < c)) { se[tid] = c; se[ixj] = a; }
        }
        __syncthreads();
      }
    }
    int take = ec < KSEL ? ec : KSEL;
    if (tid < take) easy_out[b * 64 + tid] = (int)(~(uint32_t)se[CAP_E - 1 - tid]);
    __syncthreads();
    if (tid == 0 && take < KSEL) {   // fewer than 50 easy: ascending non-easy tail
      int slot = take;
      for (int n = 0; n < NPIX && slot < KSEL; ++n)
        if (scores[b * NPIX + n] >= SENT_NONE) easy_out[b * 64 + slot++] = n;
    }
    __syncthreads();
  } else {
    // slow exact path (never taken on bench data): iterative global max-selection
    uint64_t prev = 0xFFFFFFFFFFFFFFFFull;
    int k = 0;
    for (; k < KSEL; ++k) {
      uint64_t lmax = 0;
      for (int i = tid; i < NPIX; i += 1024) {
        uint32_t v = scores[b * NPIX + i];
        if (v < SENT_NONE) {
          uint64_t key = ((uint64_t)v << 32) | (uint32_t)(~(uint32_t)i);
          if (key < prev && key > lmax) lmax = key;
        }
      }
      for (int off = 32; off; off >>= 1) {
        uint64_t o = __shfl_down(lmax, off);
        if (o > lmax) lmax = o;
      }
      if (lane == 0) wred[wv] = lmax;
      __syncthreads();
      if (tid == 0) {
        uint64_t m = 0;
        for (int w = 0; w < 16; ++w) if (wred[w] > m) m = wred[w];
        s_win = m;
      }
      __syncthreads();
      uint64_t win = s_win;
      __syncthreads();
      if (win == 0) break;
      if (tid == 0) easy_out[b * 64 + k] = (int)(~(uint32_t)win);
      prev = win;
    }
    if (tid == 0 && k < KSEL) {
      int slot = k;
      for (int n = 0; n < NPIX && slot < KSEL; ++n)
        if (scores[b * NPIX + n] >= SENT_NONE) easy_out[b * 64 + slot++] = n;
    }
    __syncthreads();
  }

  // ---------------- HARD ----------------
  if (fast_hard) {
    for (int m = tid; m < CAP_H; m += 1024)
      shd[m] = (m < hc) ? hcand[b * CAP_H + m] : 0xFFFFFFFFu;
    __syncthreads();
    for (int k2 = 2; k2 <= CAP_H; k2 <<= 1) {
      for (int j = k2 >> 1; j > 0; j >>= 1) {
        for (int m = tid; m < CAP_H; m += 1024) {
          int ixj = m ^ j;
          if (ixj > m) {
            uint32_t a = shd[m], c = shd[ixj];
            bool asc = ((m & k2) == 0);
            if (asc ? (a > c) : (a < c)) { shd[m] = c; shd[ixj] = a; }
          }
        }
        __syncthreads();
      }
    }
    int take = hc < KSEL ? hc : KSEL;
    if (tid < take) hard_out[b * 64 + tid] = (int)shd[tid];
    __syncthreads();
    if (tid == 0 && take < KSEL) {   // fewer than 50 hard: ascending non-hard tail
      int slot = take;
      for (int n = 0; n < NPIX && slot < KSEL; ++n)
        if (scores[b * NPIX + n] != SENT_HARD) hard_out[b * 64 + slot++] = n;
    }
    __syncthreads();
  } else {
    // slow exact path: iterative global min-selection over hard indices
    int prev = -1;
    int k = 0;
    for (; k < KSEL; ++k) {
      uint32_t lmin = 0xFFFFFFFFu;
      for (int i = tid; i < NPIX; i += 1024) {
        uint32_t v = scores[b * NPIX + i];
        if (v == SENT_HARD && i > prev && (uint32_t)i < lmin) lmin = (uint32_t)i;
      }
      for (int off = 32; off; off >>= 1) {
        uint32_t o = (uint32_t)__shfl_down(lmin, off);
        if (o < lmin) lmin = o;
      }
      if (lane == 0) wred[wv] = lmin;
      __syncthreads();
      if (tid == 0) {
        uint32_t m = 0xFFFFFFFFu;
        for (int w = 0; w < 16; ++w) if ((uint32_t)wred[w] < m) m = (uint32_t)wred[w];
        s_win = m;
      }
      __syncthreads();
      uint32_t win = (uint32_t)s_win;
      __syncthreads();
      if (win == 0xFFFFFFFFu) break;
      if (tid == 0) hard_out[b * 64 + k] = (int)win;
      prev = (int)win;
    }
    if (tid == 0 && k < KSEL) {
      int slot = k;
      for (int n = 0; n < NPIX && slot < KSEL; ++n)
        if (scores[b * NPIX + n] != SENT_HARD) hard_out[b * 64 + slot++] = n;
    }
    __syncthreads();
  }
}

// Pass 3: gather 200 rows of D=128 from feats (layout [B,D,N]) and L2-normalize.
__global__ void k_gather(const float* __restrict__ feats, const int* __restrict__ easy_out,
                         const int* __restrict__ hard_out, float* __restrict__ A) {
  int r = blockIdx.x;          // A[2i+v] = X_[v][i]
  int d = threadIdx.x;         // 0..127
  int v = r & 1, i = r >> 1;
  int n = (i < KSEL) ? easy_out[v * 64 + i] : hard_out[v * 64 + (i - KSEL)];
  float val = feats[((size_t)(v * 128 + d)) * NPIX + (size_t)n];
  float sq = val * val;
  for (int off = 32; off; off >>= 1) sq += __shfl_down(sq, off);
  __shared__ float wsum[2];
  __shared__ float s_inv;
  if ((d & 63) == 0) wsum[d >> 6] = sq;
  __syncthreads();
  if (d == 0) s_inv = 1.0f / fmaxf(sqrtf(wsum[0] + wsum[1]), 1e-12f);
  __syncthreads();
  A[r * 128 + d] = val * s_inv;
}

// Pass 4: per-row contrastive terms, atomically accumulated into the scalar out.
__global__ __launch_bounds__(256) void k_loss(const float* __restrict__ A,
                                              float* __restrict__ out) {
  int r = blockIdx.x;   // 0..199
  int c = threadIdx.x;  // 0..255
  __shared__ float arow[128];
  __shared__ float red[256];
  if (c < 128) arow[c] = A[r * 128 + c];
  __syncthreads();
  bool valid = c < 200;
  float logit = -1e30f;
  if (valid) {
    const float* Ac = A + c * 128;
    float dot = 0.f;
#pragma unroll 8
    for (int d = 0; d < 128; ++d) dot += arow[d] * Ac[d];
    logit = dot * 10.0f;      // / BASE_TEMP (0.1)
  }
  red[c] = logit;
  __syncthreads();
  for (int s = 128; s; s >>= 1) { if (c < s) { float o = red[c + s]; if (o > red[c]) red[c] = o; } __syncthreads(); }
  float M = red[0];
  __syncthreads();
  float e = valid ? expf(logit - M) : 0.f;
  bool sameblk = valid && ((r / 100) == (c / 100));
  red[c] = (valid && !sameblk) ? e : 0.f;   // neg_mask = 1 - mask0
  __syncthreads();
  for (int s = 128; s; s >>= 1) { if (c < s) red[c] += red[c + s]; __syncthreads(); }
  float neg = red[0];
  __syncthreads();
  bool msk = sameblk && !(r < 100 && c == r);   // mask0 * logits_mask
  red[c] = msk ? ((logit - M) - logf(e + neg)) : 0.f;
  __syncthreads();
  for (int s = 128; s; s >>= 1) { if (c < s) red[c] += red[c + s]; __syncthreads(); }
  if (c == 0) {
    float denom = (r < 100) ? 99.f : 100.f;
    // -(mean_lpp / TEMP).mean() accumulated across 200 rows
    atomicAdd(out, -(red[0] / denom) / (20.0f * 200.0f));
  }
}

extern "C" void kernel_launch(void* const* d_in, const int* in_sizes, int n_in,
                              void* d_out, int out_size, void* d_ws, size_t ws_size,
                              hipStream_t stream) {
  const float* feats  = (const float*)d_in[0];
  const int* labels   = (const int*)d_in[1];
  const int* predict  = (const int*)d_in[2];
  float* out = (float*)d_out;

  char* ws = (char*)d_ws;
  uint32_t* scores = (uint32_t*)ws;                            // 1 MiB
  uint64_t* ecand  = (uint64_t*)(ws + (size_t)2 * NPIX * 4);   // 2*1024 u64 = 16 KB
  uint32_t* hcand  = (uint32_t*)((char*)ecand + 2 * CAP_E * 8);// 2*2048 u32 = 16 KB
  int* cnts  = (int*)((char*)hcand + 2 * CAP_H * 4);           // 8*CSTR int
  int* easy  = cnts + 8 * CSTR;                                // 2*64 int
  int* hard  = easy + 2 * 64;                                  // 2*64 int
  float* A   = (float*)(hard + 2 * 64);                        // 200*128 f32

  // Batch keys: key(42) = (0,42); split -> blocks (0,2) and (1,3) (host-side, deterministic).
  uint32_t a0, a1, b0, b1;
  tf_block(0u, 42u, 0u, 2u, a0, a1);
  tf_block(0u, 42u, 1u, 3u, b0, b1);
  // keys[0] = (a0, b0), keys[1] = (a1, b1)

  k_zero<<<1, 256, 0, stream>>>(cnts, out);
  k_scores<<<(2 * NPIX) / 512, 512, 0, stream>>>(labels, predict, scores, ecand, hcand, cnts, a0, b0, a1, b1);
  k_select<<<2, 1024, 0, stream>>>(scores, ecand, hcand, cnts, easy, hard);
  k_gather<<<200, 128, 0, stream>>>(feats, easy, hard, A);
  k_loss<<<200, 256, 0, stream>>>(A, out);
}

// Round 6
// 202.504 us; speedup vs baseline: 8.4934x; 1.0668x over previous
//
#include <hip/hip_runtime.h>
#include <stdint.h>

#define NPIX   131072      // 32*64*64 per batch
#define HALFN  65536
#define KSEL   50
#define CAP_E  1024        // easy candidate cap (u >= THR)
#define CAP_H  2048        // hard prefix length / cap
#define THR    0.99f
#define CSTR   32          // counter stride in ints (128 B: one cacheline per counter)
#define SENT_HARD 0xFFFFFFFFu
#define SENT_NONE 0xFFFFFFFEu

__host__ __device__ __forceinline__ uint32_t rotl32(uint32_t v, int d) {
  return (v << d) | (v >> (32 - d));
}

// JAX Threefry-2x32 block (20 rounds), matches jax/_src/prng.py exactly.
__host__ __device__ __forceinline__ void tf_block(uint32_t k0, uint32_t k1,
                                                  uint32_t c0, uint32_t c1,
                                                  uint32_t& o0, uint32_t& o1) {
  uint32_t ks2 = k0 ^ k1 ^ 0x1BD11BDAu;
  uint32_t x0 = c0 + k0, x1 = c1 + k1;
#define TF_R(r) { x0 += x1; x1 = rotl32(x1, (r)); x1 ^= x0; }
  TF_R(13) TF_R(15) TF_R(26) TF_R(6)   x0 += k1;  x1 += ks2 + 1u;
  TF_R(17) TF_R(29) TF_R(16) TF_R(24)  x0 += ks2; x1 += k0  + 2u;
  TF_R(13) TF_R(15) TF_R(26) TF_R(6)   x0 += k0;  x1 += k1  + 3u;
  TF_R(17) TF_R(29) TF_R(16) TF_R(24)  x0 += k1;  x1 += ks2 + 4u;
  TF_R(13) TF_R(15) TF_R(26) TF_R(6)   x0 += ks2; x1 += k0  + 5u;
#undef TF_R
  o0 = x0; o1 = x1;
}

__global__ void k_zero(int* cnts, float* out) {
  int i = threadIdx.x;
  if (i < 8 * CSTR) cnts[i] = 0;
  if (i == 0) out[0] = 0.f;
}

// Pass 1: classify, Threefry uniform, block-aggregated compaction.
// cnts[(b*4 + {0:easy_total,1:easy_cand,2:hard_total,3:hard_cand}) * CSTR]
__global__ __launch_bounds__(512) void k_scores(
    const int* __restrict__ labels, const int* __restrict__ predict,
    uint32_t* __restrict__ scores, uint64_t* __restrict__ ecand,
    uint32_t* __restrict__ hcand, int* __restrict__ cnts,
    uint32_t k00, uint32_t k01, uint32_t k10, uint32_t k11) {
  int gid = blockIdx.x * blockDim.x + threadIdx.x;   // grid exact
  int b = gid >> 17;
  int n = gid & (NPIX - 1);
  int tid = threadIdx.x, wv = tid >> 6, lane = tid & 63;
  int yh = labels[gid], yp = predict[gid];
  bool is_easy = (yh == 1 && yp == 1);
  bool is_hard = (yh == 0 && yp == 0);
  uint32_t sval = SENT_NONE;
  float u = -1.f;
  if (is_easy) {
    uint32_t ka = b ? k10 : k00, kb = b ? k11 : k01;
    uint32_t o0, o1, bits;
    if (n < HALFN) { tf_block(ka, kb, (uint32_t)n, (uint32_t)(n + HALFN), o0, o1); bits = o0; }
    else           { tf_block(ka, kb, (uint32_t)(n - HALFN), (uint32_t)n, o0, o1); bits = o1; }
    u = __uint_as_float((bits >> 9) | 0x3F800000u) - 1.0f;   // jax uniform [0,1)
    sval = __float_as_uint(u);
  } else if (is_hard) {
    sval = SENT_HARD;
  }
  scores[gid] = sval;

  bool cand_e = is_easy && (u >= THR);
  bool cand_h = is_hard && (n < CAP_H);
  uint64_t bal_e  = __ballot(is_easy), bal_h  = __ballot(is_hard);
  uint64_t bal_ec = __ballot(cand_e),  bal_hc = __ballot(cand_h);

  __shared__ int we[8], wh[8], wec[8], whc[8];
  __shared__ int base_ec, base_hc;
  if (lane == 0) {
    we[wv]  = __popcll(bal_e);  wh[wv]  = __popcll(bal_h);
    wec[wv] = __popcll(bal_ec); whc[wv] = __popcll(bal_hc);
  }
  __syncthreads();
  if (tid == 0) {
    int te = 0, th = 0, tec = 0, thc = 0;
    for (int w = 0; w < 8; ++w) { te += we[w]; th += wh[w]; tec += wec[w]; thc += whc[w]; }
    if (te) atomicAdd(&cnts[(b * 4 + 0) * CSTR], te);
    if (th) atomicAdd(&cnts[(b * 4 + 2) * CSTR], th);
    base_ec = tec ? atomicAdd(&cnts[(b * 4 + 1) * CSTR], tec) : 0;
    base_hc = thc ? atomicAdd(&cnts[(b * 4 + 3) * CSTR], thc) : 0;
  }
  __syncthreads();
  if (cand_e) {
    int pre = 0;
    for (int w = 0; w < wv; ++w) pre += wec[w];
    int p = base_ec + pre + __popcll(bal_ec & ((1ull << lane) - 1));
    if (p < CAP_E)
      ecand[b * CAP_E + p] = ((uint64_t)sval << 32) | (uint32_t)(~(uint32_t)n);
  }
  if (cand_h) {
    int pre = 0;
    for (int w = 0; w < wv; ++w) pre += whc[w];
    int p = base_hc + pre + __popcll(bal_hc & ((1ull << lane) - 1));
    hcand[b * CAP_H + p] = (uint32_t)n;   // <= CAP_H guaranteed (subset of n<CAP_H)
  }
}

__device__ __forceinline__ bool cond_eval(uint32_t s, int cid) {
  // 0: non-easy, 1: hard, 2: non-hard
  return cid == 0 ? (s >= SENT_NONE) : (cid == 1 ? (s == SENT_HARD) : (s != SENT_HARD));
}

// want-th (0-based) smallest index n with cond over one batch's scores; 128-thread block.
// foundcnt = number actually found (= want+1 on success).
__device__ int nth_min_pred(const uint32_t* __restrict__ sc, int want, int cid,
                            int tid, int lane, int wv, uint32_t* s_w32, int* foundcnt) {
  int prev = -1;
  int k = 0;
  for (; k <= want; ++k) {
    uint32_t lmin = 0xFFFFFFFFu;
    for (int m = tid; m < NPIX; m += 128) {
      if (cond_eval(sc[m], cid) && m > prev && (uint32_t)m < lmin) lmin = (uint32_t)m;
    }
    for (int off = 32; off; off >>= 1) {
      uint32_t o = (uint32_t)__shfl_down(lmin, off);
      if (o < lmin) lmin = o;
    }
    if (lane == 0) s_w32[wv] = lmin;
    __syncthreads();
    uint32_t g = s_w32[0] < s_w32[1] ? s_w32[0] : s_w32[1];
    __syncthreads();
    if (g == 0xFFFFFFFFu) break;
    prev = (int)g;
  }
  *foundcnt = k;
  return prev;
}

// Pass 2 (fused select+gather): one block per output row. Rank-selects this row's
// pixel index from the candidate buffers, gathers feats column, L2-normalizes.
__global__ __launch_bounds__(128) void k_selgather(
    const uint32_t* __restrict__ scores, const uint64_t* __restrict__ ecand,
    const uint32_t* __restrict__ hcand, const int* __restrict__ cnts,
    const float* __restrict__ feats, float* __restrict__ A) {
  int r = blockIdx.x;          // row 0..199; A[2i+v] = X_[v][i]
  int tid = threadIdx.x;       // 0..127
  int lane = tid & 63, wv = tid >> 6;
  int v = r & 1, i = r >> 1;
  int b = v;
  const uint32_t* sc = scores + (size_t)b * NPIX;

  __shared__ uint64_t se[CAP_E];     // 8 KB
  __shared__ uint32_t shd[CAP_H];    // 8 KB
  __shared__ uint32_t s_w32[2];
  __shared__ uint64_t s_w64[2];
  __shared__ int s_n;

  int et = cnts[(b * 4 + 0) * CSTR], ec = cnts[(b * 4 + 1) * CSTR];
  int ht = cnts[(b * 4 + 2) * CSTR], hc = cnts[(b * 4 + 3) * CSTR];

  if (i < KSEL) {
    // ---------------- easy row: rank i of top_k ----------------
    int eneed = et < KSEL ? et : KSEL;
    bool fast = (ec <= CAP_E) && (ec >= eneed);
    if (fast) {
      int take = ec < KSEL ? ec : KSEL;
      if (i < take) {
        for (int t = tid; t < ec; t += 128) se[t] = ecand[b * CAP_E + t];
        __syncthreads();
        for (int t = tid; t < ec; t += 128) {
          uint64_t mine = se[t];
          int rank = 0;
          for (int j = 0; j < ec; ++j) rank += (se[j] > mine);
          if (rank == i) s_n = (int)(~(uint32_t)mine);
        }
        __syncthreads();
      } else {
        // take == et < 50: tail = (i-et)-th smallest non-easy index
        int fc;
        int nsel = nth_min_pred(sc, i - take, 0, tid, lane, wv, s_w32, &fc);
        if (tid == 0) s_n = nsel;
        __syncthreads();
      }
    } else {
      // slow exact: iterative max-selection over easy keys (never taken on bench data)
      uint64_t prev = 0xFFFFFFFFFFFFFFFFull;
      int found = 0, nsel = -1;
      for (int k = 0; k <= i; ++k) {
        uint64_t lmax = 0;
        for (int m = tid; m < NPIX; m += 128) {
          uint32_t s = sc[m];
          if (s < SENT_NONE) {
            uint64_t key = ((uint64_t)s << 32) | (uint32_t)(~(uint32_t)m);
            if (key < prev && key > lmax) lmax = key;
          }
        }
        for (int off = 32; off; off >>= 1) {
          uint64_t o = __shfl_down(lmax, off);
          if (o > lmax) lmax = o;
        }
        if (lane == 0) s_w64[wv] = lmax;
        __syncthreads();
        uint64_t g = s_w64[0] > s_w64[1] ? s_w64[0] : s_w64[1];
        __syncthreads();
        if (g == 0) break;
        prev = g; found = k + 1;
        if (k == i) nsel = (int)(~(uint32_t)g);
      }
      if (nsel < 0) {
        int fc;
        nsel = nth_min_pred(sc, i - found, 0, tid, lane, wv, s_w32, &fc);
      }
      if (tid == 0) s_n = nsel;
      __syncthreads();
    }
  } else {
    // ---------------- hard row: j-th smallest hard index ----------------
    int j = i - KSEL;
    int hneed = ht < KSEL ? ht : KSEL;
    bool fast = (hc >= hneed);   // hc <= CAP_H always
    if (fast) {
      int take = hc < KSEL ? hc : KSEL;
      if (j < take) {
        for (int t = tid; t < hc; t += 128) shd[t] = hcand[b * CAP_H + t];
        __syncthreads();
        for (int t = tid; t < hc; t += 128) {
          uint32_t mine = shd[t];
          int rank = 0;
          for (int m = 0; m < hc; ++m) rank += (shd[m] < mine);
          if (rank == j) s_n = (int)mine;
        }
        __syncthreads();
      } else {
        // take == ht < 50: tail = (j-ht)-th smallest non-hard index
        int fc;
        int nsel = nth_min_pred(sc, j - take, 2, tid, lane, wv, s_w32, &fc);
        if (tid == 0) s_n = nsel;
        __syncthreads();
      }
    } else {
      // slow exact (never taken on bench data)
      int fc = 0;
      int nsel = nth_min_pred(sc, j, 1, tid, lane, wv, s_w32, &fc);
      if (fc < j + 1) {
        int fc2;
        nsel = nth_min_pred(sc, j - fc, 2, tid, lane, wv, s_w32, &fc2);
      }
      if (tid == 0) s_n = nsel;
      __syncthreads();
    }
  }

  int n = s_n;
  // gather + L2-normalize (feats layout [B, D=128, NPIX])
  float val = feats[((size_t)(v * 128 + tid)) * NPIX + (size_t)n];
  float sq = val * val;
  for (int off = 32; off; off >>= 1) sq += __shfl_down(sq, off);
  __shared__ float wsum[2];
  __shared__ float s_inv;
  if (lane == 0) wsum[wv] = sq;
  __syncthreads();
  if (tid == 0) s_inv = 1.0f / fmaxf(sqrtf(wsum[0] + wsum[1]), 1e-12f);
  __syncthreads();
  A[r * 128 + tid] = val * s_inv;
}

// Pass 3: per-row contrastive terms, atomically accumulated into the scalar out.
__global__ __launch_bounds__(256) void k_loss(const float* __restrict__ A,
                                              float* __restrict__ out) {
  int r = blockIdx.x;   // 0..199
  int c = threadIdx.x;  // 0..255
  __shared__ float arow[128];
  __shared__ float red[256];
  if (c < 128) arow[c] = A[r * 128 + c];
  __syncthreads();
  bool valid = c < 200;
  float logit = -1e30f;
  if (valid) {
    const float* Ac = A + c * 128;
    float dot = 0.f;
#pragma unroll 8
    for (int d = 0; d < 128; ++d) dot += arow[d] * Ac[d];
    logit = dot * 10.0f;      // / BASE_TEMP (0.1)
  }
  red[c] = logit;
  __syncthreads();
  for (int s = 128; s; s >>= 1) { if (c < s) { float o = red[c + s]; if (o > red[c]) red[c] = o; } __syncthreads(); }
  float M = red[0];
  __syncthreads();
  float e = valid ? expf(logit - M) : 0.f;
  bool sameblk = valid && ((r / 100) == (c / 100));
  red[c] = (valid && !sameblk) ? e : 0.f;   // neg_mask = 1 - mask0
  __syncthreads();
  for (int s = 128; s; s >>= 1) { if (c < s) red[c] += red[c + s]; __syncthreads(); }
  float neg = red[0];
  __syncthreads();
  bool msk = sameblk && !(r < 100 && c == r);   // mask0 * logits_mask
  red[c] = msk ? ((logit - M) - logf(e + neg)) : 0.f;
  __syncthreads();
  for (int s = 128; s; s >>= 1) { if (c < s) red[c] += red[c + s]; __syncthreads(); }
  if (c == 0) {
    float denom = (r < 100) ? 99.f : 100.f;
    // -(mean_lpp / TEMP).mean() accumulated across 200 rows
    atomicAdd(out, -(red[0] / denom) / (20.0f * 200.0f));
  }
}

extern "C" void kernel_launch(void* const* d_in, const int* in_sizes, int n_in,
                              void* d_out, int out_size, void* d_ws, size_t ws_size,
                              hipStream_t stream) {
  const float* feats  = (const float*)d_in[0];
  const int* labels   = (const int*)d_in[1];
  const int* predict  = (const int*)d_in[2];
  float* out = (float*)d_out;

  char* ws = (char*)d_ws;
  uint32_t* scores = (uint32_t*)ws;                            // 1 MiB
  uint64_t* ecand  = (uint64_t*)(ws + (size_t)2 * NPIX * 4);   // 2*1024 u64 = 16 KB
  uint32_t* hcand  = (uint32_t*)((char*)ecand + 2 * CAP_E * 8);// 2*2048 u32 = 16 KB
  int* cnts  = (int*)((char*)hcand + 2 * CAP_H * 4);           // 8*CSTR int
  float* A   = (float*)(cnts + 8 * CSTR);                      // 200*128 f32

  // Batch keys: key(42) = (0,42); split -> blocks (0,2) and (1,3) (host-side, deterministic).
  uint32_t a0, a1, b0, b1;
  tf_block(0u, 42u, 0u, 2u, a0, a1);
  tf_block(0u, 42u, 1u, 3u, b0, b1);
  // keys[0] = (a0, b0), keys[1] = (a1, b1)

  k_zero<<<1, 256, 0, stream>>>(cnts, out);
  k_scores<<<(2 * NPIX) / 512, 512, 0, stream>>>(labels, predict, scores, ecand, hcand, cnts, a0, b0, a1, b1);
  k_selgather<<<200, 128, 0, stream>>>(scores, ecand, hcand, cnts, feats, A);
  k_loss<<<200, 256, 0, stream>>>(A, out);
}